// Round 5
// baseline (41.536 us; speedup 1.0000x reference)
//
#include <hip/hip_runtime.h>

// B=4, LQ=256, LK=512, DQ=DK=DV=256, H=128
#define B_   4
#define LQ_  256
#define LK_  512
#define DQK_ 256
#define DV_  256
#define H_   128

#define TANH_C 2.8853900817779268f   // 2*log2(e): tanh(x) = 1 - 2/(exp2(TANH_C*x)+1)
#define L2E    1.4426950408889634f
#define NQBLK (B_ * LQ_ / 8)         // 128 q-proj blocks (TILE=8)
#define NKBLK (B_ * LK_ / 8)         // 256 k-proj blocks

// ---------------------------------------------------------------------------
// proj_kernel: fused q+k projection. TILE=8 rows/block, 128 threads (t = h).
// Rows staged in LDS (broadcast reads); W reads coalesced over t.
//   q blocks -> eq  [B*LQ, H]  = exp2(TANH_C * q@Wq)
//   k blocks -> ekT [B, H, LK] = exp2(TANH_C * k@Wk)   (transposed)
// ---------------------------------------------------------------------------
__global__ __launch_bounds__(128) void proj_kernel(const float* __restrict__ Q,
                                                   const float* __restrict__ K,
                                                   const float* __restrict__ Wq,
                                                   const float* __restrict__ Wk,
                                                   float* __restrict__ eq,
                                                   float* __restrict__ ekT) {
    __shared__ float rows[8 * DQK_];           // 8 KB
    const int blk = blockIdx.x;
    const bool isq = blk < NQBLK;
    const float* in = isq ? Q  : K;
    const float* W  = isq ? Wq : Wk;
    const int r0 = (isq ? blk : blk - NQBLK) * 8;
    const int t  = threadIdx.x;

    const float4* in4 = reinterpret_cast<const float4*>(in + (size_t)r0 * DQK_);
    float4* r4 = reinterpret_cast<float4*>(rows);
#pragma unroll
    for (int i = 0; i < 4; ++i) r4[t + 128 * i] = in4[t + 128 * i];
    __syncthreads();

    float acc[8];
#pragma unroll
    for (int j = 0; j < 8; ++j) acc[j] = 0.f;

#pragma unroll 2
    for (int d4 = 0; d4 < DQK_ / 4; ++d4) {
        float w0 = W[(size_t)(4 * d4 + 0) * H_ + t];   // coalesced
        float w1 = W[(size_t)(4 * d4 + 1) * H_ + t];
        float w2 = W[(size_t)(4 * d4 + 2) * H_ + t];
        float w3 = W[(size_t)(4 * d4 + 3) * H_ + t];
#pragma unroll
        for (int j = 0; j < 8; ++j) {
            float4 r = *reinterpret_cast<const float4*>(&rows[j * DQK_ + 4 * d4]); // LDS broadcast
            acc[j] = fmaf(r.x, w0, fmaf(r.y, w1, fmaf(r.z, w2, fmaf(r.w, w3, acc[j]))));
        }
    }
    float e[8];
#pragma unroll
    for (int j = 0; j < 8; ++j) e[j] = __builtin_amdgcn_exp2f(acc[j] * TANH_C);

    if (isq) {
#pragma unroll
        for (int j = 0; j < 8; ++j)
            eq[(size_t)(r0 + j) * H_ + t] = e[j];
    } else {
        const int b  = r0 >> 9;
        const int k0 = r0 & (LK_ - 1);
        float* o = ekT + ((size_t)(b * H_ + t)) * LK_ + k0;
        *reinterpret_cast<float4*>(o)     = make_float4(e[0], e[1], e[2], e[3]);
        *reinterpret_cast<float4*>(o + 4) = make_float4(e[4], e[5], e[6], e[7]);
    }
}

// ---------------------------------------------------------------------------
// attn_kernel: 512 blocks x 512 threads (8 waves, 2 blocks/CU).
//   block -> (b, qt): b = (blk&1) | (((blk>>8)&1)<<1), qt = (blk>>1)&127
//   (so co-resident block pairs (i, i+256) carry different batches -> balance)
//   thread -> (qi = t>>8, kq = t&255 owning k = {2kq, 2kq+1})
//  Phase B: p += wv[h] * rcp(fma(Eq[qi][h], Ek[h][k], 1))  (1 trans/elem)
//           Eq/wv via wave-uniform s_loads; Ek via float2 loads, unroll 8.
//           score = -2*p (+const cancels in softmax); k>=valid -> -1e6.
//  Phase C: per-row masked softmax (waves 0-3 row 0, waves 4-7 row 1).
//  Phase D: thread (half = t>>8, v = t&255) accumulates both rows over
//           k = half, half+2, ... < valid (interleaved for balance).
// ---------------------------------------------------------------------------
__global__ __launch_bounds__(512, 4) void attn_kernel(
    const float* __restrict__ eq,          // [B*LQ, H]
    const float* __restrict__ ekT,         // [B, H, LK]
    const float* __restrict__ wv,          // [H]
    const float* __restrict__ values,      // [B, LK, DV]
    const int*   __restrict__ valid_lens,  // [B]
    float* __restrict__ out) {             // [B*LQ, DV]
    __shared__ float sc[LK_][2];           // 4 KB
    __shared__ float part[2][2][DV_];      // 4 KB
    __shared__ float red[8];
    __shared__ float redm[2];
    __shared__ float inv_s[2];

    const int blk = blockIdx.x;
    const int b   = (blk & 1) | (((blk >> 8) & 1) << 1);
    const int qt  = (blk >> 1) & 127;
    const int t   = threadIdx.x;
    const int valid = valid_lens[b];

    const int qi = __builtin_amdgcn_readfirstlane(t >> 8);   // 0/1 wave-uniform
    const int kq = t & 255;                                  // k-pair index

    // ---- Phase B: scores for k = 2kq, 2kq+1 at row qi ----
    float s0 = -1e6f, s1 = -1e6f;
    {
        const float* eqr = eq + (size_t)(b * LQ_ + qt * 2 + qi) * H_;  // uniform -> s_load
        const float* ekp = ekT + (size_t)b * H_ * LK_ + 2 * kq;
        if (2 * kq < valid) {
            float p0 = 0.f, p1 = 0.f;
#pragma unroll 8
            for (int h = 0; h < H_; ++h) {
                float2 ek = *reinterpret_cast<const float2*>(ekp + (size_t)h * LK_);
                float q = eqr[h];      // s_load (K$)
                float w = wv[h];       // s_load (K$)
                p0 = fmaf(w, __builtin_amdgcn_rcpf(fmaf(q, ek.x, 1.f)), p0);
                p1 = fmaf(w, __builtin_amdgcn_rcpf(fmaf(q, ek.y, 1.f)), p1);
            }
            s0 = -2.f * p0;
            s1 = (2 * kq + 1 < valid) ? -2.f * p1 : -1e6f;
        }
    }

    // ---- Phase C: masked softmax per row (waves 0-3 -> qi 0, 4-7 -> qi 1) ----
    {
        float m = fmaxf(s0, s1);
#pragma unroll
        for (int off = 32; off; off >>= 1) m = fmaxf(m, __shfl_down(m, off, 64));
        if ((t & 63) == 0) red[t >> 6] = m;
    }
    __syncthreads();
    if (t < 2) {
        redm[t] = fmaxf(fmaxf(red[4 * t], red[4 * t + 1]),
                        fmaxf(red[4 * t + 2], red[4 * t + 3]));
    }
    __syncthreads();
    {
        const float m = redm[qi];
        float e0 = __builtin_amdgcn_exp2f((s0 - m) * L2E);
        float e1 = __builtin_amdgcn_exp2f((s1 - m) * L2E);
        sc[2 * kq][qi]     = e0;
        sc[2 * kq + 1][qi] = e1;
        float ss = e0 + e1;
#pragma unroll
        for (int off = 32; off; off >>= 1) ss += __shfl_down(ss, off, 64);
        if ((t & 63) == 0) red[t >> 6] = ss;
    }
    __syncthreads();
    if (t < 2) {
        inv_s[t] = 1.f / (red[4 * t] + red[4 * t + 1] + red[4 * t + 2] + red[4 * t + 3]);
    }
    __syncthreads();

    // ---- Phase D: out = attn @ values (k interleaved by half for balance) ----
    {
        const int v    = t & 255;
        const int half = t >> 8;
        const float* vb = values + (size_t)b * LK_ * DV_ + v;
        float a0 = 0.f, a1 = 0.f;
#pragma unroll 8
        for (int k = half; k < valid; k += 2) {
            float2 w  = *reinterpret_cast<const float2*>(&sc[k][0]);  // LDS broadcast
            float val = vb[(size_t)k * DV_];                          // coalesced over v
            a0 = fmaf(w.x, val, a0);
            a1 = fmaf(w.y, val, a1);
        }
        part[half][0][v] = a0;
        part[half][1][v] = a1;
    }
    __syncthreads();
    {
        const int v = t & 255;
        out[(size_t)(b * LQ_ + qt * 2 + qi) * DV_ + v] =
            (part[0][qi][v] + part[1][qi][v]) * inv_s[qi];
    }
}

extern "C" void kernel_launch(void* const* d_in, const int* in_sizes, int n_in,
                              void* d_out, int out_size, void* d_ws, size_t ws_size,
                              hipStream_t stream) {
    const float* queries    = (const float*)d_in[0];  // [B, LQ, DQ]
    const float* keys       = (const float*)d_in[1];  // [B, LK, DK]
    const float* values     = (const float*)d_in[2];  // [B, LK, DV]
    const float* Wq         = (const float*)d_in[3];  // [DQ, H]
    const float* Wk         = (const float*)d_in[4];  // [DK, H]
    const float* wv         = (const float*)d_in[5];  // [H]
    const int*   valid_lens = (const int*)d_in[6];    // [B]
    float* out = (float*)d_out;

    float* eq  = (float*)d_ws;                   // [B*LQ, H]   512 KB
    float* ekT = eq + (size_t)B_ * LQ_ * H_;     // [B, H, LK]  1 MB

    proj_kernel<<<NQBLK + NKBLK, 128, 0, stream>>>(queries, keys, Wq, Wk, eq, ekT);
    attn_kernel<<<2 * B_ * LQ_ / 4, 512, 0, stream>>>(eq, ekT, wv, values, valid_lens, out);
}